// Round 5
// baseline (2667.621 us; speedup 1.0000x reference)
//
#include <hip/hip_runtime.h>
#include <hip/hip_bf16.h>
#include <stdint.h>

typedef __bf16 bf16;
typedef bf16 bf16x8 __attribute__((ext_vector_type(8)));
typedef bf16 bf16x4 __attribute__((ext_vector_type(4)));
typedef float f32x4 __attribute__((ext_vector_type(4)));
typedef unsigned long long u64;

#define NB 8
#define NH 36
#define NW 100
#define YS 44
#define XSZ 108
#define PIX 28800

#define AS1 __attribute__((address_space(1)))
#define AS3 __attribute__((address_space(3)))

// async 16B global->LDS DMA. Dest = wave-uniform base + lane*16.
__device__ __forceinline__ void g2l16(const bf16* g, bf16* l) {
    __builtin_amdgcn_global_load_lds((const AS1 void*)g, (AS3 void*)l, 16, 0, 0);
}

// ---- DPP lane-rotation helpers (VALU pipe) ----
// AMD DPP semantics: row_shr:1 = lane i <- lane i-1; row_shl:1 = lane i <- lane i+1
// (lane 15 of each 16-lane row invalid -> takes OLD with bound_ctrl=false);
// row_ror:N = lane i <- lane (i-N) mod 16.
// shl1: lane i <- src lane i+1 within each 16-lane row; lane 15 <- old lane 15.
__device__ __forceinline__ bf16x8 dpp_shl1(bf16x8 oldv, bf16x8 srcv) {
    union { bf16x8 v; int i[4]; } o, s, d;
    o.v = oldv; s.v = srcv;
#pragma unroll
    for (int k = 0; k < 4; k++)
        d.i[k] = __builtin_amdgcn_update_dpp(o.i[k], s.i[k], 0x101, 0xF, 0xF, false);
    return d.v;
}
// rol1: lane i <- lane (i+1) mod 16 within each row (= row_ror:15).
__device__ __forceinline__ bf16x8 dpp_rol1(bf16x8 srcv) {
    union { bf16x8 v; int i[4]; } s, d;
    s.v = srcv;
#pragma unroll
    for (int k = 0; k < 4; k++)
        d.i[k] = __builtin_amdgcn_update_dpp(s.i[k], s.i[k], 0x12F, 0xF, 0xF, false);
    return d.v;
}
// ror8: lane i <- lane (i+8) mod 16 (self-inverse; undoes 8x rol1).
__device__ __forceinline__ bf16x8 dpp_ror8(bf16x8 srcv) {
    union { bf16x8 v; int i[4]; } s, d;
    s.v = srcv;
#pragma unroll
    for (int k = 0; k < 4; k++)
        d.i[k] = __builtin_amdgcn_update_dpp(s.i[k], s.i[k], 0x128, 0xF, 0xF, false);
    return d.v;
}

// ---------------- workspace layout ----------------
static constexpr size_t OFF_XP = 0;
static constexpr size_t SZ_XP  = (size_t)NB*YS*XSZ*512*2;
static constexpr size_t OFF_HP = OFF_XP + SZ_XP;
static constexpr size_t SZ_HP  = (size_t)NB*YS*XSZ*128*2;
static constexpr size_t OFF_A1 = OFF_HP + SZ_HP;
static constexpr size_t SZ_A1  = (size_t)1024*4608*2;
static constexpr size_t OFF_A2 = OFF_A1 + SZ_A1;
static constexpr size_t SZ_A2  = (size_t)128*1024*2;
static constexpr size_t OFF_AW = OFF_A2 + SZ_A2;
static constexpr size_t SZ_AW  = (size_t)4*9*128*128*2;
static constexpr size_t OFF_H1 = OFF_AW + SZ_AW;
static constexpr size_t SZ_H1  = (size_t)PIX*1024*2;
static constexpr size_t OFF_S1 = OFF_H1 + SZ_H1;
static constexpr size_t OFF_T1 = OFF_S1 + 4096;
static constexpr size_t OFF_S2 = OFF_T1 + 4096;
static constexpr size_t OFF_T2 = OFF_S2 + 512;
static constexpr size_t OFF_H5 = OFF_T2 + 512;
static constexpr size_t SZ_H5  = (size_t)NB*5*3600*4;
static constexpr size_t OFF_P  = OFF_H5 + SZ_H5;
static constexpr size_t OFF_F  = OFF_P + SZ_H5;
static constexpr size_t OFF_G  = OFF_F + 144128;
static constexpr size_t OFF_BAR = OFF_G + 4096;      // 8 x u32 (legacy, unused by msg now)

// ---------------- prep kernels ----------------
__global__ __launch_bounds__(256) void zero_k(uint4* __restrict__ p, int n) {
    int i = blockIdx.x * 256 + threadIdx.x;
    if (i < n) p[i] = uint4{0u, 0u, 0u, 0u};
}

__global__ __launch_bounds__(256) void prep_x(const float* __restrict__ x, bf16* __restrict__ xp) {
    int bid = blockIdx.x;
    int xc = bid & 3;  int r = bid >> 2;
    int cc = r & 15;   r >>= 4;
    int yo = r % 36;   int b = r / 36;
    int ci0 = cc * 32, xo0 = xc * 32;
    int wdt = 100 - xo0; if (wdt > 32) wdt = 32;
    __shared__ bf16 T[32 * 33];
    int t = threadIdx.x;
    int cl = t >> 5, xl = t & 31;
    if (xl < wdt) {
#pragma unroll
        for (int i = 0; i < 4; i++) {
            int ci = ci0 + cl + 8 * i;
            T[(cl + 8 * i) * 33 + xl] = (bf16)x[((size_t)(b * 512 + ci) * 36 + yo) * 100 + xo0 + xl];
        }
    }
    __syncthreads();
    if (t < 128) {
        int xo2 = t >> 2, oct = t & 3;
        if (xo2 < wdt) {
            bf16x8 vv;
#pragma unroll
            for (int j = 0; j < 8; j++) vv[j] = T[(oct * 8 + j) * 33 + xo2];
            *(bf16x8*)(xp + ((size_t)((b * YS + yo + 4) * XSZ) + xo0 + xo2 + 4) * 512 + ci0 + oct * 8) = vv;
        }
    }
}

__global__ __launch_bounds__(256) void prep_w1a(const float* __restrict__ w, bf16* __restrict__ A) {
    int co = blockIdx.x;
    __shared__ bf16 Wl[4608];
    const float* src = w + (size_t)co * 4608;
    for (int v = threadIdx.x; v < 4608; v += 256) Wl[v] = (bf16)src[v];
    __syncthreads();
    bf16* dst = A + (size_t)co * 4608;
    for (int v = threadIdx.x; v < 4608; v += 256) {
        int rr = v >> 9, ci = v & 511;
        dst[v] = Wl[ci * 9 + rr];
    }
}

__global__ __launch_bounds__(256) void prep_w1b(const float* __restrict__ w, bf16* __restrict__ A) {
    int i = blockIdx.x * 256 + threadIdx.x;
    if (i < 131072) A[i] = (bf16)w[i];
}

__global__ __launch_bounds__(256) void prep_msg(const float* __restrict__ w0, const float* __restrict__ w1,
                                                const float* __restrict__ w2m, const float* __restrict__ w3,
                                                bf16* __restrict__ Aw) {
    int idx = blockIdx.x * 256 + threadIdx.x;
    if (idx >= 4 * 147456) return;
    int w = idx / 147456, r = idx % 147456;
    int t9 = r / 16384, r2 = r % 16384;
    int co = r2 >> 7, ci = r2 & 127;
    const float* s = (w == 0) ? w0 : (w == 1) ? w1 : (w == 2) ? w2m : w3;
    Aw[idx] = (bf16)s[(co * 128 + ci) * 9 + t9];
}

__global__ __launch_bounds__(256) void prep_bn(const float* g1, const float* b1, const float* m1, const float* v1,
                                               const float* g2, const float* b2i, const float* m2, const float* v2,
                                               float* s1, float* t1, float* s2, float* t2,
                                               unsigned* bar) {
    int i = blockIdx.x * 256 + threadIdx.x;
    if (i < 1024) {
        float s = g1[i] / sqrtf(v1[i] + 1e-5f);
        s1[i] = s; t1[i] = b1[i] - m1[i] * s;
    } else if (i < 1152) {
        int c = i - 1024;
        float s = g2[c] / sqrtf(v2[c] + 1e-5f);
        s2[c] = s; t2[c] = b2i[c] - m2[c] * s;
    } else if (i < 1160) {
        bar[i - 1152] = 0u;                 // legacy reset (msg no longer uses it)
    }
}

// ---------------- conv1: implicit-im2col GEMM, global_load_lds + swizzled LDS ----------------
__device__ __forceinline__ void c1_koff(int ch, int& k0, int& xoff) {
    int ky = ch / 48, rem = ch - ky * 48;
    int kx = rem >> 4, c0 = (rem & 15) << 5;
    k0 = (ky * 3 + kx) * 512 + c0;
    xoff = (ky * XSZ + kx) * 2048 + c0;
}

__device__ __forceinline__ bf16x8 lds_frag(const bf16* S, int row, int q) {
    return *(const bf16x8*)(S + row * 32 + (((q ^ (row >> 1)) & 3) * 8));
}

__global__ __launch_bounds__(256) void conv1_gemm(const bf16* __restrict__ A, const bf16* __restrict__ xp,
                                                  const float* __restrict__ s1, const float* __restrict__ t1,
                                                  bf16* __restrict__ h1) {
    __shared__ __align__(16) bf16 SH[17408];
    bf16* As = SH;
    bf16* Bs = SH + 4096;
    const int t = threadIdx.x;
    const int pt = blockIdx.x, ct = blockIdx.y;
    const int co0 = ct * 128, p0 = pt * 128;
    const int wid = t >> 6, lane = t & 63;

    int aOff[2], bOff[2], ldsOff[2];
#pragma unroll
    for (int j = 0; j < 2; j++) {
        int p = wid * 128 + j * 64 + lane;
        int row = p >> 2;
        int oc = (p & 3) ^ ((p >> 3) & 3);
        aOff[j] = (co0 + row) * 4608 + oc * 8;
        int px = p0 + row;
        int b = px / 3600, rr = px % 3600;
        int y = rr / 100, xx = rr % 100;
        bOff[j] = ((b * YS + y) * XSZ + xx) * 512 + oc * 8;
        ldsOff[j] = (wid * 128 + j * 64) * 8;
    }

    const int mbase = (wid & 1) * 64, nbase = (wid >> 1) * 64;
    const int l15 = lane & 15, q = lane >> 4;

    f32x4 acc[4][4];
#pragma unroll
    for (int i = 0; i < 4; i++)
#pragma unroll
        for (int j = 0; j < 4; j++) acc[i][j] = f32x4{0.f, 0.f, 0.f, 0.f};

    for (int ch = 0; ch < 144; ch++) {
        int k0, xoff;
        c1_koff(ch, k0, xoff);
        __syncthreads();
#pragma unroll
        for (int j = 0; j < 2; j++) {
            g2l16(A + aOff[j] + k0, As + ldsOff[j]);
            g2l16(xp + bOff[j] + xoff, Bs + ldsOff[j]);
        }
        __syncthreads();
        bf16x8 af[4], bfv[4];
#pragma unroll
        for (int mt = 0; mt < 4; mt++) af[mt] = lds_frag(As, mbase + mt * 16 + l15, q);
#pragma unroll
        for (int nt = 0; nt < 4; nt++) bfv[nt] = lds_frag(Bs, nbase + nt * 16 + l15, q);
#pragma unroll
        for (int mt = 0; mt < 4; mt++)
#pragma unroll
            for (int nt = 0; nt < 4; nt++)
                acc[mt][nt] = __builtin_amdgcn_mfma_f32_16x16x32_bf16(af[mt], bfv[nt], acc[mt][nt], 0, 0, 0);
    }

    __syncthreads();
#pragma unroll
    for (int mt = 0; mt < 4; mt++) {
        int co = co0 + mbase + mt * 16 + q * 4;
        f32x4 sc = *(const f32x4*)(s1 + co);
        f32x4 tc = *(const f32x4*)(t1 + co);
#pragma unroll
        for (int nt = 0; nt < 4; nt++) {
            int pxl = nbase + nt * 16 + l15;
            bf16x4 o;
#pragma unroll
            for (int r = 0; r < 4; r++) {
                float v = acc[mt][nt][r] * sc[r] + tc[r];
                o[r] = (bf16)(v > 0.f ? v : 0.f);
            }
            *(bf16x4*)(SH + pxl * 136 + mbase + mt * 16 + q * 4) = o;
        }
    }
    __syncthreads();
#pragma unroll
    for (int i = 0; i < 8; i++) {
        int v = t + 256 * i;
        int pxl = v >> 4, c16 = v & 15;
        *(uint4*)(h1 + (size_t)(p0 + pxl) * 1024 + co0 + c16 * 8) = *(const uint4*)(SH + pxl * 136 + c16 * 8);
    }
}

// ---------------- conv2: 1x1 1024->128 ----------------
__global__ __launch_bounds__(256) void conv2_gemm(const bf16* __restrict__ A2, const bf16* __restrict__ h1,
                                                  const float* __restrict__ s2, const float* __restrict__ t2,
                                                  bf16* __restrict__ hp) {
    __shared__ __align__(16) bf16 SH[17408];
    bf16* As = SH;
    bf16* Bs = SH + 4096;
    const int t = threadIdx.x;
    const int p0 = blockIdx.x * 128;
    const int wid = t >> 6, lane = t & 63;

    int aOff[2], bOff[2], ldsOff[2];
#pragma unroll
    for (int j = 0; j < 2; j++) {
        int p = wid * 128 + j * 64 + lane;
        int row = p >> 2;
        int oc = (p & 3) ^ ((p >> 3) & 3);
        aOff[j] = row * 1024 + oc * 8;
        bOff[j] = (p0 + row) * 1024 + oc * 8;
        ldsOff[j] = (wid * 128 + j * 64) * 8;
    }
    const int mbase = (wid & 1) * 64, nbase = (wid >> 1) * 64;
    const int l15 = lane & 15, q = lane >> 4;

    f32x4 acc[4][4];
#pragma unroll
    for (int i = 0; i < 4; i++)
#pragma unroll
        for (int j = 0; j < 4; j++) acc[i][j] = f32x4{0.f, 0.f, 0.f, 0.f};

    for (int ch = 0; ch < 32; ch++) {
        int k0 = ch * 32;
        __syncthreads();
#pragma unroll
        for (int j = 0; j < 2; j++) {
            g2l16(A2 + aOff[j] + k0, As + ldsOff[j]);
            g2l16(h1 + bOff[j] + k0, Bs + ldsOff[j]);
        }
        __syncthreads();
        bf16x8 af[4], bfv[4];
#pragma unroll
        for (int mt = 0; mt < 4; mt++) af[mt] = lds_frag(As, mbase + mt * 16 + l15, q);
#pragma unroll
        for (int nt = 0; nt < 4; nt++) bfv[nt] = lds_frag(Bs, nbase + nt * 16 + l15, q);
#pragma unroll
        for (int mt = 0; mt < 4; mt++)
#pragma unroll
            for (int nt = 0; nt < 4; nt++)
                acc[mt][nt] = __builtin_amdgcn_mfma_f32_16x16x32_bf16(af[mt], bfv[nt], acc[mt][nt], 0, 0, 0);
    }

    __syncthreads();
#pragma unroll
    for (int mt = 0; mt < 4; mt++) {
        int co = mbase + mt * 16 + q * 4;
        f32x4 sc = *(const f32x4*)(s2 + co);
        f32x4 tc = *(const f32x4*)(t2 + co);
#pragma unroll
        for (int nt = 0; nt < 4; nt++) {
            int pxl = nbase + nt * 16 + l15;
            bf16x4 o;
#pragma unroll
            for (int r = 0; r < 4; r++) {
                float v = acc[mt][nt][r] * sc[r] + tc[r];
                o[r] = (bf16)(v > 0.f ? v : 0.f);
            }
            *(bf16x4*)(SH + pxl * 136 + co) = o;
        }
    }
    __syncthreads();
#pragma unroll
    for (int i = 0; i < 8; i++) {
        int v = t + 256 * i;
        int pxl = v >> 4, c16 = v & 15;
        int p = p0 + pxl;
        int b = p / 3600, rr = p % 3600;
        int y = rr / 100, xx = rr % 100;
        *(uint4*)(hp + (size_t)((b * YS + y + 4) * XSZ + xx + 4) * 128 + c16 * 8) = *(const uint4*)(SH + pxl * 136 + c16 * 8);
    }
}

// ---------------- fused message passes: ONE block (512 thr, 8 waves) per batch ----------------
// Round-1 structure (8 waves, 2/SIMD, wave = 16-co slice over full n) was
// LDS-b128-throughput-bound: 36 reads per tile re-fetch a 24-row window
// whose taps overlap 15/16. This version reads each aligned 16-row fragment
// ONCE (2 live frags, W/X ping-pong) and derives the 9 tap operands by DPP
// row_shl:1 on the VALU pipe (lane i <- lane i+1), injecting the lane-15
// boundary value from a rotate-left-1 chain of the next fragment
// (update_dpp old-operand = injection). After 8 rotations, row_ror:8
// restores the companion pristine for the next tile.
// LDS reads/wave/step: 252 -> 32. MFMA values & accumulation order identical.
__device__ __forceinline__ bf16x8 awfrag2(const bf16* __restrict__ Aw, int ch, int cs, int l15, int q) {
    int t9 = ch >> 2, c0 = (ch & 3) << 5;
    return *(const bf16x8*)(Aw + (size_t)((t9 * 128 + cs * 16 + l15) << 7) + c0 + q * 8);
}

template <int I, int NT>
__device__ __forceinline__ void tile_step(const bf16x8* __restrict__ a, bf16x8* Wf, bf16x8* Xf,
                                          f32x4& acc, const bf16* __restrict__ bp, int lo) {
    // tap 0: pristine W = F(I), rows I*16+l15
#pragma unroll
    for (int j = 0; j < 4; j++)
        acc = __builtin_amdgcn_mfma_f32_16x16x32_bf16(a[j], Wf[j], acc, 0, 0, 0);
    // rotate-left chain init on X = F(I+1): after rol1, lane15 = X[0] (= row I*16+16)
#pragma unroll
    for (int j = 0; j < 4; j++) Xf[j] = dpp_rol1(Xf[j]);
    // tap 1
#pragma unroll
    for (int j = 0; j < 4; j++) {
        Wf[j] = dpp_shl1(Xf[j], Wf[j]);
        acc = __builtin_amdgcn_mfma_f32_16x16x32_bf16(a[4 + j], Wf[j], acc, 0, 0, 0);
        Xf[j] = dpp_rol1(Xf[j]);
    }
    // taps 2..8
#pragma unroll
    for (int t9 = 2; t9 < 9; t9++) {
#pragma unroll
        for (int j = 0; j < 4; j++) {
            Wf[j] = dpp_shl1(Xf[j], Wf[j]);
            acc = __builtin_amdgcn_mfma_f32_16x16x32_bf16(a[t9 * 4 + j], Wf[j], acc, 0, 0, 0);
            if (t9 < 8) Xf[j] = dpp_rol1(Xf[j]);
        }
    }
    // W is dead -> refill with F(I+2) for the tile after next
    if constexpr (I + 2 <= NT) {
#pragma unroll
        for (int j = 0; j < 4; j++)
            Wf[j] = *(const bf16x8*)(bp + (I + 2) * 16 * 136 + lo + j * 32);
    }
    // restore X (8x rol1 applied) to pristine F(I+1) = next tile's W
    if constexpr (I + 1 < NT) {
#pragma unroll
        for (int j = 0; j < 4; j++) Xf[j] = dpp_ror8(Xf[j]);
    }
}

template <int AX, int RV>
__device__ void phase1cu(const bf16* __restrict__ Aw, bf16* __restrict__ hpb,
                         bf16*& bp, bf16*& bn) {
    constexpr int STEPS = (AX == 2) ? NH : NW;
    constexpr int NLIM  = (AX == 2) ? NW : NH;
    constexpr int NT    = (AX == 2) ? 7 : 3;        // 16-wide n-tiles covering NLIM
    const int t = threadIdx.x, wid = t >> 6, lane = t & 63, l15 = lane & 15, q = lane >> 4;

    // wave's 16-co weight slice -> registers (same in all waves' co-slices)
    bf16x8 a[36];
#pragma unroll
    for (int ch = 0; ch < 36; ch++) a[ch] = awfrag2(Aw, ch, wid, l15, q);

    const int co = wid * 16 + q * 4;
    const int pos0 = RV ? (STEPS - 1) : 0;

    // phase-start staging of initial line into bp
    if (AX == 2) {
        // rows 0..107 = padded x-line of row pos0 (pads in hp are zero).
        // rows 108..127 are never written by any phase -> remain zero.
        const bf16* src = hpb + (size_t)(pos0 + 4) * XSZ * 128;
        for (int v = t; v < XSZ * 16; v += 512) {
            int px = v >> 4, c = (v & 15) * 8;
            *(uint4*)(bp + px * 136 + c) = *(const uint4*)(src + px * 128 + c);
        }
    } else {
        // zero rows 40..55 of BOTH buffers (dirtied by AX2; y-pad + read slack),
        // stage y rows 0..39 (rows 0..3 zero pads never written by AX2).
        for (int v = t; v < 2 * 16 * 17; v += 512) {
            int bsel = v >= 272;
            int r2 = v - bsel * 272;
            bf16* dst = bsel ? bn : bp;
            *(uint4*)(dst + (40 + (r2 / 17)) * 136 + (r2 % 17) * 8) = uint4{0u, 0u, 0u, 0u};
        }
        const bf16* src = hpb + (size_t)(pos0 + 4) * 128;
        for (int v = t; v < 40 * 16; v += 512) {
            int ys = v >> 4, c = (v & 15) * 8;
            *(uint4*)(bp + ys * 136 + c) = *(const uint4*)(src + (size_t)ys * XSZ * 128 + c);
        }
    }
    __syncthreads();

    const int lo = l15 * 136 + q * 8;

    for (int s = 1; s < STEPS; s++) {
        const int pos = RV ? (STEPS - 1 - s) : s;

        // prefetch own-co 'cur' values (L2-hot; completes under the MFMAs)
        int goff[NT];
        u64 curv[NT];
#pragma unroll
        for (int i = 0; i < NT; i++) {
            int n = i * 16 + l15;
            goff[i] = (AX == 2) ? ((pos + 4) * XSZ + n + 4) * 128 + co
                                : ((n + 4) * XSZ + pos + 4) * 128 + co;
            curv[i] = 0;
            if (n < NLIM) curv[i] = *(const u64*)(hpb + goff[i]);
        }

        // W = F(0), X = F(1)
        bf16x8 W[4], X[4];
#pragma unroll
        for (int j = 0; j < 4; j++) {
            W[j] = *(const bf16x8*)(bp + lo + j * 32);
            X[j] = *(const bf16x8*)(bp + 16 * 136 + lo + j * 32);
        }

        f32x4 acc[NT];
#pragma unroll
        for (int i = 0; i < NT; i++) acc[i] = f32x4{0.f, 0.f, 0.f, 0.f};

        tile_step<0, NT>(a, W, X, acc[0], bp, lo);
        if constexpr (NT > 1) tile_step<1, NT>(a, X, W, acc[1], bp, lo);
        if constexpr (NT > 2) tile_step<2, NT>(a, W, X, acc[2], bp, lo);
        if constexpr (NT > 3) tile_step<3, NT>(a, X, W, acc[3], bp, lo);
        if constexpr (NT > 4) tile_step<4, NT>(a, W, X, acc[4], bp, lo);
        if constexpr (NT > 5) tile_step<5, NT>(a, X, W, acc[5], bp, lo);
        if constexpr (NT > 6) tile_step<6, NT>(a, W, X, acc[6], bp, lo);

        // epilogue: new = cur + relu(acc); -> global hp AND next line buffer
#pragma unroll
        for (int i = 0; i < NT; i++) {
            int n = i * 16 + l15;
            if (n < NLIM) {
                bf16x4 cur = *(bf16x4*)&curv[i];
                bf16x4 o;
#pragma unroll
                for (int r = 0; r < 4; r++) {
                    float v = acc[i][r];
                    v = v > 0.f ? v : 0.f;
                    o[r] = (bf16)((float)cur[r] + v);
                }
                *(u64*)(hpb + goff[i]) = *(u64*)&o;
                *(u64*)(bn + (n + 4) * 136 + co) = *(u64*)&o;
            }
        }
        __syncthreads();
        bf16* tmp = bp; bp = bn; bn = tmp;
    }
}

__global__ __launch_bounds__(512, 2) void msg_fused(const bf16* __restrict__ Aw, bf16* __restrict__ hp) {
    __shared__ __align__(16) bf16 BUF[2][128 * 136];   // 2 x 34 KB ping-pong line buffers
    const int batch = blockIdx.x;
    bf16* hpb = hp + (size_t)batch * YS * XSZ * 128;
    // zero both buffers once (pad rows must start zero)
    for (int v = threadIdx.x; v < 2 * 128 * 17; v += 512)
        ((uint4*)BUF)[v] = uint4{0u, 0u, 0u, 0u};
    __syncthreads();
    bf16* bp = BUF[0];
    bf16* bn = BUF[1];
    phase1cu<2, 0>(Aw + 0 * 147456, hpb, bp, bn);
    phase1cu<2, 1>(Aw + 1 * 147456, hpb, bp, bn);
    phase1cu<3, 0>(Aw + 2 * 147456, hpb, bp, bn);
    phase1cu<3, 1>(Aw + 3 * 147456, hpb, bp, bn);
}

// ---------------- conv3 (1x1 128->5) + bias + softmax ----------------
__global__ __launch_bounds__(256) void conv3_softmax(const bf16* __restrict__ hp, const float* __restrict__ w2,
                                                     const float* __restrict__ b2, float* __restrict__ h5,
                                                     float* __restrict__ Pp) {
    int idx = blockIdx.x * 256 + threadIdx.x;
    if (idx >= PIX) return;
    int b = idx / 3600, rr = idx % 3600;
    int y = rr / 100, xx = rr % 100;
    const bf16* src = hp + ((size_t)(b * YS + y + 4) * XSZ + xx + 4) * 128;
    float a[5] = {b2[0], b2[1], b2[2], b2[3], b2[4]};
    for (int c8 = 0; c8 < 128; c8 += 8) {
        bf16x8 hv = *(const bf16x8*)(src + c8);
#pragma unroll
        for (int j = 0; j < 8; j++) {
            float hf = (float)hv[j];
            int c = c8 + j;
#pragma unroll
            for (int o = 0; o < 5; o++) a[o] += hf * w2[o * 128 + c];
        }
    }
    float mx = a[0];
#pragma unroll
    for (int o = 1; o < 5; o++) mx = a[o] > mx ? a[o] : mx;
    float e[5], sum = 0.f;
#pragma unroll
    for (int o = 0; o < 5; o++) { e[o] = expf(a[o] - mx); sum += e[o]; }
    float inv = 1.f / sum;
#pragma unroll
    for (int o = 0; o < 5; o++) {
        h5[(size_t)(b * 5 + o) * 3600 + rr] = a[o];
        Pp[(size_t)(b * 5 + o) * 3600 + rr] = e[o] * inv;
    }
}

__global__ __launch_bounds__(256) void pool_k(const float* __restrict__ Pp, float* __restrict__ F) {
    int idx = blockIdx.x * 256 + threadIdx.x;
    if (idx >= 36000) return;
    int xxp = idx % 50, r = idx / 50;
    int yyp = r % 18, bj = r / 18;
    int b = bj / 5, j = bj % 5;
    const float* Pb = Pp + (size_t)bj * 3600;
    float v = 0.25f * (Pb[(2 * yyp) * 100 + 2 * xxp] + Pb[(2 * yyp) * 100 + 2 * xxp + 1] +
                       Pb[(2 * yyp + 1) * 100 + 2 * xxp] + Pb[(2 * yyp + 1) * 100 + 2 * xxp + 1]);
    F[(size_t)b * 4500 + j * 900 + yyp * 50 + xxp] = v;
}

__global__ __launch_bounds__(64) void fc1_k(const float* __restrict__ F, const float* __restrict__ w,
                                            const float* __restrict__ bias, float* __restrict__ G) {
    int co = blockIdx.x;
    int lane = threadIdx.x;
    const float* wr = w + (size_t)co * 4500;
    float a[8] = {0.f, 0.f, 0.f, 0.f, 0.f, 0.f, 0.f, 0.f};
    for (int k = lane; k < 4500; k += 64) {
        float wv = wr[k];
#pragma unroll
        for (int b = 0; b < 8; b++) a[b] += wv * F[b * 4500 + k];
    }
#pragma unroll
    for (int b = 0; b < 8; b++) {
        float r = a[b];
        for (int off = 32; off; off >>= 1) r += __shfl_down(r, off);
        if (lane == 0) {
            float v = r + bias[co];
            G[b * 128 + co] = v > 0.f ? v : 0.f;
        }
    }
}

__global__ __launch_bounds__(64) void fc2_k(const float* __restrict__ G, const float* __restrict__ w,
                                            const float* __restrict__ bias, float* __restrict__ out) {
    int t = threadIdx.x;
    if (t >= 32) return;
    int b = t >> 2, j = t & 3;
    float a = bias[j];
    for (int c = 0; c < 128; c++) a += G[b * 128 + c] * w[j * 128 + c];
    out[9216000 + b * 4 + j] = 1.f / (1.f + expf(-a));
}

__global__ __launch_bounds__(256) void upsample_k(const float* __restrict__ h5, float* __restrict__ out) {
    int idx = blockIdx.x * 256 + threadIdx.x;
    if (idx >= 2304000) return;
    int xq = idx % 200, r = idx / 200;
    int yo = r % 288, bj = r / 288;
    const float* src = h5 + (size_t)bj * 3600;
    float py = yo * (35.0f / 287.0f);
    int i0 = (int)py; if (i0 > 34) i0 = 34;
    float fh = py - (float)i0;
    const float* r0 = src + i0 * 100;
    const float* r1 = r0 + 100;
    float4 o;
    float res[4];
#pragma unroll
    for (int e = 0; e < 4; e++) {
        int xo = xq * 4 + e;
        float px = xo * (99.0f / 799.0f);
        int j0 = (int)px; if (j0 > 98) j0 = 98;
        float fw = px - (float)j0;
        float aa = r0[j0] * (1.f - fh) + r1[j0] * fh;
        float bb = r0[j0 + 1] * (1.f - fh) + r1[j0 + 1] * fh;
        res[e] = aa * (1.f - fw) + bb * fw;
    }
    o.x = res[0]; o.y = res[1]; o.z = res[2]; o.w = res[3];
    *(float4*)(out + (size_t)idx * 4) = o;
}

// ---------------- launcher ----------------
extern "C" void kernel_launch(void* const* d_in, const int* in_sizes, int n_in,
                              void* d_out, int out_size, void* d_ws, size_t ws_size,
                              hipStream_t stream) {
    (void)in_sizes; (void)n_in; (void)out_size; (void)ws_size;
    const float* x    = (const float*)d_in[0];
    const float* w1a  = (const float*)d_in[1];
    const float* bn1g = (const float*)d_in[2];
    const float* bn1b = (const float*)d_in[3];
    const float* bn1m = (const float*)d_in[4];
    const float* bn1v = (const float*)d_in[5];
    const float* w1b  = (const float*)d_in[6];
    const float* bn2g = (const float*)d_in[7];
    const float* bn2b = (const float*)d_in[8];
    const float* bn2m = (const float*)d_in[9];
    const float* bn2v = (const float*)d_in[10];
    const float* wud  = (const float*)d_in[11];
    const float* wdu  = (const float*)d_in[12];
    const float* wlr  = (const float*)d_in[13];
    const float* wrl  = (const float*)d_in[14];
    const float* w2   = (const float*)d_in[15];
    const float* b2   = (const float*)d_in[16];
    const float* fc1w = (const float*)d_in[17];
    const float* fc1b = (const float*)d_in[18];
    const float* fc2w = (const float*)d_in[19];
    const float* fc2b = (const float*)d_in[20];
    float* out = (float*)d_out;
    char* ws = (char*)d_ws;
    bf16* xp = (bf16*)(ws + OFF_XP);
    bf16* hp = (bf16*)(ws + OFF_HP);
    bf16* A1 = (bf16*)(ws + OFF_A1);
    bf16* A2 = (bf16*)(ws + OFF_A2);
    bf16* Aw = (bf16*)(ws + OFF_AW);
    bf16* h1 = (bf16*)(ws + OFF_H1);
    float* s1 = (float*)(ws + OFF_S1);
    float* t1 = (float*)(ws + OFF_T1);
    float* s2 = (float*)(ws + OFF_S2);
    float* t2 = (float*)(ws + OFF_T2);
    float* h5 = (float*)(ws + OFF_H5);
    float* Pp = (float*)(ws + OFF_P);
    float* Ff = (float*)(ws + OFF_F);
    float* Gg = (float*)(ws + OFF_G);
    unsigned* bar = (unsigned*)(ws + OFF_BAR);

    int nzero = (int)((SZ_XP + SZ_HP) / 16);
    zero_k<<<(nzero + 255) / 256, 256, 0, stream>>>((uint4*)ws, nzero);
    prep_x<<<18432, 256, 0, stream>>>(x, xp);
    prep_w1a<<<1024, 256, 0, stream>>>(w1a, A1);
    prep_w1b<<<512, 256, 0, stream>>>(w1b, A2);
    prep_msg<<<2304, 256, 0, stream>>>(wud, wdu, wlr, wrl, Aw);
    prep_bn<<<5, 256, 0, stream>>>(bn1g, bn1b, bn1m, bn1v, bn2g, bn2b, bn2m, bn2v, s1, t1, s2, t2, bar);

    conv1_gemm<<<dim3(225, 8), 256, 0, stream>>>(A1, xp, s1, t1, h1);
    conv2_gemm<<<225, 256, 0, stream>>>(A2, h1, s2, t2, hp);

    msg_fused<<<8, 512, 0, stream>>>(Aw, hp);

    conv3_softmax<<<113, 256, 0, stream>>>(hp, w2, b2, h5, Pp);
    pool_k<<<141, 256, 0, stream>>>(Pp, Ff);
    fc1_k<<<128, 64, 0, stream>>>(Ff, fc1w, fc1b, Gg);
    fc2_k<<<1, 64, 0, stream>>>(Gg, fc2w, fc2b, out);
    upsample_k<<<9000, 256, 0, stream>>>(h5, out);
}

// Round 6
// 1938.874 us; speedup vs baseline: 1.3759x; 1.3759x over previous
//
#include <hip/hip_runtime.h>
#include <hip/hip_bf16.h>
#include <stdint.h>

typedef __bf16 bf16;
typedef bf16 bf16x8 __attribute__((ext_vector_type(8)));
typedef bf16 bf16x4 __attribute__((ext_vector_type(4)));
typedef float f32x4 __attribute__((ext_vector_type(4)));
typedef unsigned long long u64;

#define NB 8
#define NH 36
#define NW 100
#define YS 44
#define XSZ 108
#define PIX 28800

#define AS1 __attribute__((address_space(1)))
#define AS3 __attribute__((address_space(3)))

// async 16B global->LDS DMA. Dest = wave-uniform base + lane*16.
__device__ __forceinline__ void g2l16(const bf16* g, bf16* l) {
    __builtin_amdgcn_global_load_lds((const AS1 void*)g, (AS3 void*)l, 16, 0, 0);
}

// ---------------- workspace layout ----------------
static constexpr size_t OFF_XP = 0;
static constexpr size_t SZ_XP  = (size_t)NB*YS*XSZ*512*2;
static constexpr size_t OFF_HP = OFF_XP + SZ_XP;
static constexpr size_t SZ_HP  = (size_t)NB*YS*XSZ*128*2;
static constexpr size_t OFF_A1 = OFF_HP + SZ_HP;
static constexpr size_t SZ_A1  = (size_t)1024*4608*2;
static constexpr size_t OFF_A2 = OFF_A1 + SZ_A1;
static constexpr size_t SZ_A2  = (size_t)128*1024*2;
static constexpr size_t OFF_AW = OFF_A2 + SZ_A2;
static constexpr size_t SZ_AW  = (size_t)4*9*128*128*2;
static constexpr size_t OFF_H1 = OFF_AW + SZ_AW;
static constexpr size_t SZ_H1  = (size_t)PIX*1024*2;
static constexpr size_t OFF_S1 = OFF_H1 + SZ_H1;
static constexpr size_t OFF_T1 = OFF_S1 + 4096;
static constexpr size_t OFF_S2 = OFF_T1 + 4096;
static constexpr size_t OFF_T2 = OFF_S2 + 512;
static constexpr size_t OFF_H5 = OFF_T2 + 512;
static constexpr size_t SZ_H5  = (size_t)NB*5*3600*4;
static constexpr size_t OFF_P  = OFF_H5 + SZ_H5;
static constexpr size_t OFF_F  = OFF_P + SZ_H5;
static constexpr size_t OFF_G  = OFF_F + 144128;
static constexpr size_t OFF_BAR = OFF_G + 4096;      // 8 x u32 (legacy, unused by msg now)

// ---------------- prep kernels ----------------
__global__ __launch_bounds__(256) void zero_k(uint4* __restrict__ p, int n) {
    int i = blockIdx.x * 256 + threadIdx.x;
    if (i < n) p[i] = uint4{0u, 0u, 0u, 0u};
}

__global__ __launch_bounds__(256) void prep_x(const float* __restrict__ x, bf16* __restrict__ xp) {
    int bid = blockIdx.x;
    int xc = bid & 3;  int r = bid >> 2;
    int cc = r & 15;   r >>= 4;
    int yo = r % 36;   int b = r / 36;
    int ci0 = cc * 32, xo0 = xc * 32;
    int wdt = 100 - xo0; if (wdt > 32) wdt = 32;
    __shared__ bf16 T[32 * 33];
    int t = threadIdx.x;
    int cl = t >> 5, xl = t & 31;
    if (xl < wdt) {
#pragma unroll
        for (int i = 0; i < 4; i++) {
            int ci = ci0 + cl + 8 * i;
            T[(cl + 8 * i) * 33 + xl] = (bf16)x[((size_t)(b * 512 + ci) * 36 + yo) * 100 + xo0 + xl];
        }
    }
    __syncthreads();
    if (t < 128) {
        int xo2 = t >> 2, oct = t & 3;
        if (xo2 < wdt) {
            bf16x8 vv;
#pragma unroll
            for (int j = 0; j < 8; j++) vv[j] = T[(oct * 8 + j) * 33 + xo2];
            *(bf16x8*)(xp + ((size_t)((b * YS + yo + 4) * XSZ) + xo0 + xo2 + 4) * 512 + ci0 + oct * 8) = vv;
        }
    }
}

__global__ __launch_bounds__(256) void prep_w1a(const float* __restrict__ w, bf16* __restrict__ A) {
    int co = blockIdx.x;
    __shared__ bf16 Wl[4608];
    const float* src = w + (size_t)co * 4608;
    for (int v = threadIdx.x; v < 4608; v += 256) Wl[v] = (bf16)src[v];
    __syncthreads();
    bf16* dst = A + (size_t)co * 4608;
    for (int v = threadIdx.x; v < 4608; v += 256) {
        int rr = v >> 9, ci = v & 511;
        dst[v] = Wl[ci * 9 + rr];
    }
}

__global__ __launch_bounds__(256) void prep_w1b(const float* __restrict__ w, bf16* __restrict__ A) {
    int i = blockIdx.x * 256 + threadIdx.x;
    if (i < 131072) A[i] = (bf16)w[i];
}

__global__ __launch_bounds__(256) void prep_msg(const float* __restrict__ w0, const float* __restrict__ w1,
                                                const float* __restrict__ w2m, const float* __restrict__ w3,
                                                bf16* __restrict__ Aw) {
    int idx = blockIdx.x * 256 + threadIdx.x;
    if (idx >= 4 * 147456) return;
    int w = idx / 147456, r = idx % 147456;
    int t9 = r / 16384, r2 = r % 16384;
    int co = r2 >> 7, ci = r2 & 127;
    const float* s = (w == 0) ? w0 : (w == 1) ? w1 : (w == 2) ? w2m : w3;
    Aw[idx] = (bf16)s[(co * 128 + ci) * 9 + t9];
}

__global__ __launch_bounds__(256) void prep_bn(const float* g1, const float* b1, const float* m1, const float* v1,
                                               const float* g2, const float* b2i, const float* m2, const float* v2,
                                               float* s1, float* t1, float* s2, float* t2,
                                               unsigned* bar) {
    int i = blockIdx.x * 256 + threadIdx.x;
    if (i < 1024) {
        float s = g1[i] / sqrtf(v1[i] + 1e-5f);
        s1[i] = s; t1[i] = b1[i] - m1[i] * s;
    } else if (i < 1152) {
        int c = i - 1024;
        float s = g2[c] / sqrtf(v2[c] + 1e-5f);
        s2[c] = s; t2[c] = b2i[c] - m2[c] * s;
    } else if (i < 1160) {
        bar[i - 1152] = 0u;                 // legacy reset (msg no longer uses it)
    }
}

// ---------------- conv1: implicit-im2col GEMM, global_load_lds + swizzled LDS ----------------
__device__ __forceinline__ void c1_koff(int ch, int& k0, int& xoff) {
    int ky = ch / 48, rem = ch - ky * 48;
    int kx = rem >> 4, c0 = (rem & 15) << 5;
    k0 = (ky * 3 + kx) * 512 + c0;
    xoff = (ky * XSZ + kx) * 2048 + c0;
}

__device__ __forceinline__ bf16x8 lds_frag(const bf16* S, int row, int q) {
    return *(const bf16x8*)(S + row * 32 + (((q ^ (row >> 1)) & 3) * 8));
}

__global__ __launch_bounds__(256) void conv1_gemm(const bf16* __restrict__ A, const bf16* __restrict__ xp,
                                                  const float* __restrict__ s1, const float* __restrict__ t1,
                                                  bf16* __restrict__ h1) {
    __shared__ __align__(16) bf16 SH[17408];
    bf16* As = SH;
    bf16* Bs = SH + 4096;
    const int t = threadIdx.x;
    const int pt = blockIdx.x, ct = blockIdx.y;
    const int co0 = ct * 128, p0 = pt * 128;
    const int wid = t >> 6, lane = t & 63;

    int aOff[2], bOff[2], ldsOff[2];
#pragma unroll
    for (int j = 0; j < 2; j++) {
        int p = wid * 128 + j * 64 + lane;
        int row = p >> 2;
        int oc = (p & 3) ^ ((p >> 3) & 3);
        aOff[j] = (co0 + row) * 4608 + oc * 8;
        int px = p0 + row;
        int b = px / 3600, rr = px % 3600;
        int y = rr / 100, xx = rr % 100;
        bOff[j] = ((b * YS + y) * XSZ + xx) * 512 + oc * 8;
        ldsOff[j] = (wid * 128 + j * 64) * 8;
    }

    const int mbase = (wid & 1) * 64, nbase = (wid >> 1) * 64;
    const int l15 = lane & 15, q = lane >> 4;

    f32x4 acc[4][4];
#pragma unroll
    for (int i = 0; i < 4; i++)
#pragma unroll
        for (int j = 0; j < 4; j++) acc[i][j] = f32x4{0.f, 0.f, 0.f, 0.f};

    for (int ch = 0; ch < 144; ch++) {
        int k0, xoff;
        c1_koff(ch, k0, xoff);
        __syncthreads();
#pragma unroll
        for (int j = 0; j < 2; j++) {
            g2l16(A + aOff[j] + k0, As + ldsOff[j]);
            g2l16(xp + bOff[j] + xoff, Bs + ldsOff[j]);
        }
        __syncthreads();
        bf16x8 af[4], bfv[4];
#pragma unroll
        for (int mt = 0; mt < 4; mt++) af[mt] = lds_frag(As, mbase + mt * 16 + l15, q);
#pragma unroll
        for (int nt = 0; nt < 4; nt++) bfv[nt] = lds_frag(Bs, nbase + nt * 16 + l15, q);
#pragma unroll
        for (int mt = 0; mt < 4; mt++)
#pragma unroll
            for (int nt = 0; nt < 4; nt++)
                acc[mt][nt] = __builtin_amdgcn_mfma_f32_16x16x32_bf16(af[mt], bfv[nt], acc[mt][nt], 0, 0, 0);
    }

    __syncthreads();
#pragma unroll
    for (int mt = 0; mt < 4; mt++) {
        int co = co0 + mbase + mt * 16 + q * 4;
        f32x4 sc = *(const f32x4*)(s1 + co);
        f32x4 tc = *(const f32x4*)(t1 + co);
#pragma unroll
        for (int nt = 0; nt < 4; nt++) {
            int pxl = nbase + nt * 16 + l15;
            bf16x4 o;
#pragma unroll
            for (int r = 0; r < 4; r++) {
                float v = acc[mt][nt][r] * sc[r] + tc[r];
                o[r] = (bf16)(v > 0.f ? v : 0.f);
            }
            *(bf16x4*)(SH + pxl * 136 + mbase + mt * 16 + q * 4) = o;
        }
    }
    __syncthreads();
#pragma unroll
    for (int i = 0; i < 8; i++) {
        int v = t + 256 * i;
        int pxl = v >> 4, c16 = v & 15;
        *(uint4*)(h1 + (size_t)(p0 + pxl) * 1024 + co0 + c16 * 8) = *(const uint4*)(SH + pxl * 136 + c16 * 8);
    }
}

// ---------------- conv2: 1x1 1024->128 ----------------
__global__ __launch_bounds__(256) void conv2_gemm(const bf16* __restrict__ A2, const bf16* __restrict__ h1,
                                                  const float* __restrict__ s2, const float* __restrict__ t2,
                                                  bf16* __restrict__ hp) {
    __shared__ __align__(16) bf16 SH[17408];
    bf16* As = SH;
    bf16* Bs = SH + 4096;
    const int t = threadIdx.x;
    const int p0 = blockIdx.x * 128;
    const int wid = t >> 6, lane = t & 63;

    int aOff[2], bOff[2], ldsOff[2];
#pragma unroll
    for (int j = 0; j < 2; j++) {
        int p = wid * 128 + j * 64 + lane;
        int row = p >> 2;
        int oc = (p & 3) ^ ((p >> 3) & 3);
        aOff[j] = row * 1024 + oc * 8;
        bOff[j] = (p0 + row) * 1024 + oc * 8;
        ldsOff[j] = (wid * 128 + j * 64) * 8;
    }
    const int mbase = (wid & 1) * 64, nbase = (wid >> 1) * 64;
    const int l15 = lane & 15, q = lane >> 4;

    f32x4 acc[4][4];
#pragma unroll
    for (int i = 0; i < 4; i++)
#pragma unroll
        for (int j = 0; j < 4; j++) acc[i][j] = f32x4{0.f, 0.f, 0.f, 0.f};

    for (int ch = 0; ch < 32; ch++) {
        int k0 = ch * 32;
        __syncthreads();
#pragma unroll
        for (int j = 0; j < 2; j++) {
            g2l16(A2 + aOff[j] + k0, As + ldsOff[j]);
            g2l16(h1 + bOff[j] + k0, Bs + ldsOff[j]);
        }
        __syncthreads();
        bf16x8 af[4], bfv[4];
#pragma unroll
        for (int mt = 0; mt < 4; mt++) af[mt] = lds_frag(As, mbase + mt * 16 + l15, q);
#pragma unroll
        for (int nt = 0; nt < 4; nt++) bfv[nt] = lds_frag(Bs, nbase + nt * 16 + l15, q);
#pragma unroll
        for (int mt = 0; mt < 4; mt++)
#pragma unroll
            for (int nt = 0; nt < 4; nt++)
                acc[mt][nt] = __builtin_amdgcn_mfma_f32_16x16x32_bf16(af[mt], bfv[nt], acc[mt][nt], 0, 0, 0);
    }

    __syncthreads();
#pragma unroll
    for (int mt = 0; mt < 4; mt++) {
        int co = mbase + mt * 16 + q * 4;
        f32x4 sc = *(const f32x4*)(s2 + co);
        f32x4 tc = *(const f32x4*)(t2 + co);
#pragma unroll
        for (int nt = 0; nt < 4; nt++) {
            int pxl = nbase + nt * 16 + l15;
            bf16x4 o;
#pragma unroll
            for (int r = 0; r < 4; r++) {
                float v = acc[mt][nt][r] * sc[r] + tc[r];
                o[r] = (bf16)(v > 0.f ? v : 0.f);
            }
            *(bf16x4*)(SH + pxl * 136 + co) = o;
        }
    }
    __syncthreads();
#pragma unroll
    for (int i = 0; i < 8; i++) {
        int v = t + 256 * i;
        int pxl = v >> 4, c16 = v & 15;
        int p = p0 + pxl;
        int b = p / 3600, rr = p % 3600;
        int y = rr / 100, xx = rr % 100;
        *(uint4*)(hp + (size_t)((b * YS + y + 4) * XSZ + xx + 4) * 128 + c16 * 8) = *(const uint4*)(SH + pxl * 136 + c16 * 8);
    }
}

// ---------------- fused message passes: ONE block (512 thr, 8 waves) per batch ----------------
// Round-1 structure (best measured): 8 waves, each owning one 16-co weight
// slice (36 frags = 144 VGPR) over the full n-range; line ping-pongs in LDS.
// NEW: line stored at stride 128 elem (256 B) with a 16B-block XOR swizzle
// block' = block ^ (row & 7) -- kills the 272B-stride bank collisions that
// cost ~4 cy per ds_read_b128 (SQ_LDS_BANK_CONFLICT 10.2M in round 1).
// For the B-read, row & 7 = (l15 + tap) & 7 is per-lane constant per tap, so
// the swizzle folds into per-tap base pointers + i*4096 immediate offsets.
// MFMA operand values and per-accumulator order are bit-identical to round 1.
__device__ __forceinline__ bf16x8 awfrag2(const bf16* __restrict__ Aw, int ch, int cs, int l15, int q) {
    int t9 = ch >> 2, c0 = (ch & 3) << 5;
    return *(const bf16x8*)(Aw + (size_t)((t9 * 128 + cs * 16 + l15) << 7) + c0 + q * 8);
}

template <int AX, int RV>
__device__ void phase1cu(const bf16* __restrict__ Aw, bf16* __restrict__ hpb,
                         bf16*& bp, bf16*& bn) {
    constexpr int STEPS = (AX == 2) ? NH : NW;
    constexpr int NLIM  = (AX == 2) ? NW : NH;
    constexpr int NT    = (AX == 2) ? 7 : 3;        // 16-wide n-tiles covering NLIM
    const int t = threadIdx.x, wid = t >> 6, lane = t & 63, l15 = lane & 15, q = lane >> 4;

    // wave's 16-co weight slice -> registers
    bf16x8 a[36];
#pragma unroll
    for (int ch = 0; ch < 36; ch++) a[ch] = awfrag2(Aw, ch, wid, l15, q);

    const int co = wid * 16 + q * 4;
    const int pos0 = RV ? (STEPS - 1) : 0;

    // phase-start staging of initial line into bp (swizzled writes)
    if (AX == 2) {
        // rows 0..107 = padded x-line of row pos0 (pads in hp are zero).
        // rows 108..127 are never written by any phase -> remain zero.
        const bf16* src = hpb + (size_t)(pos0 + 4) * XSZ * 128;
        for (int v = t; v < XSZ * 16; v += 512) {
            int px = v >> 4, c16 = v & 15;
            *(uint4*)((char*)bp + px * 256 + ((c16 ^ (px & 7)) << 4)) =
                *(const uint4*)(src + px * 128 + c16 * 8);
        }
    } else {
        // zero rows 40..55 of BOTH buffers (dirtied by AX2; read slack),
        // stage y rows 0..39 (rows 0..3 zero pads never written by AX2).
        for (int v = t; v < 2 * 16 * 16; v += 512) {
            int bsel = v >= 256;
            int r2 = v - bsel * 256;
            bf16* dst = bsel ? bn : bp;
            *(uint4*)((char*)dst + (40 + (r2 >> 4)) * 256 + ((r2 & 15) << 4)) = uint4{0u, 0u, 0u, 0u};
        }
        const bf16* src = hpb + (size_t)(pos0 + 4) * 128;
        for (int v = t; v < 40 * 16; v += 512) {
            int ys = v >> 4, c16 = v & 15;
            *(uint4*)((char*)bp + ys * 256 + ((c16 ^ (ys & 7)) << 4)) =
                *(const uint4*)(src + (size_t)ys * XSZ * 128 + c16 * 8);
        }
    }
    __syncthreads();

    // epilogue write base: row = n+4 = i*16 + l15 + 4; row&7 = (l15+4)&7
    const int xe = (l15 + 4) & 7;
    const int ebase = (l15 + 4) * 256 + (((2 * wid + (q >> 1)) ^ xe) << 4) + ((q & 1) << 3);

    for (int s = 1; s < STEPS; s++) {
        const int pos = RV ? (STEPS - 1 - s) : s;

        // prefetch own-co 'cur' values (L2-hot; completes under the MFMAs)
        int goff[NT];
        u64 curv[NT];
#pragma unroll
        for (int i = 0; i < NT; i++) {
            int n = i * 16 + l15;
            goff[i] = (AX == 2) ? ((pos + 4) * XSZ + n + 4) * 128 + co
                                : ((n + 4) * XSZ + pos + 4) * 128 + co;
            curv[i] = 0;
            if (n < NLIM) curv[i] = *(const u64*)(hpb + goff[i]);
        }

        f32x4 acc[NT];
#pragma unroll
        for (int i = 0; i < NT; i++) acc[i] = f32x4{0.f, 0.f, 0.f, 0.f};

        const char* bpB = (const char*)bp;
#pragma unroll
        for (int t9 = 0; t9 < 9; t9++) {
            const int rx = l15 + t9;
            const int x7 = rx & 7;
            const int e0 = (x7 & 4) << 4;                       // 64*(x7>>2)
            const int base = rx * 256 + ((q ^ (x7 & 3)) << 4);
            const char* p0 = bpB + (base + e0);                 // cquad 0 (and 2 at +128)
            const char* p1 = bpB + (base + (64 - e0));          // cquad 1 (and 3 at +128)
#pragma unroll
            for (int i = 0; i < NT; i++) {
                bf16x8 b0 = *(const bf16x8*)(p0 + i * 4096);
                acc[i] = __builtin_amdgcn_mfma_f32_16x16x32_bf16(a[4 * t9 + 0], b0, acc[i], 0, 0, 0);
                bf16x8 b1 = *(const bf16x8*)(p1 + i * 4096);
                acc[i] = __builtin_amdgcn_mfma_f32_16x16x32_bf16(a[4 * t9 + 1], b1, acc[i], 0, 0, 0);
                bf16x8 b2 = *(const bf16x8*)(p0 + i * 4096 + 128);
                acc[i] = __builtin_amdgcn_mfma_f32_16x16x32_bf16(a[4 * t9 + 2], b2, acc[i], 0, 0, 0);
                bf16x8 b3 = *(const bf16x8*)(p1 + i * 4096 + 128);
                acc[i] = __builtin_amdgcn_mfma_f32_16x16x32_bf16(a[4 * t9 + 3], b3, acc[i], 0, 0, 0);
            }
        }

        // epilogue: new = cur + relu(acc); -> global hp AND next line buffer
#pragma unroll
        for (int i = 0; i < NT; i++) {
            int n = i * 16 + l15;
            if (n < NLIM) {
                bf16x4 cur = *(bf16x4*)&curv[i];
                bf16x4 o;
#pragma unroll
                for (int r = 0; r < 4; r++) {
                    float v = acc[i][r];
                    v = v > 0.f ? v : 0.f;
                    o[r] = (bf16)((float)cur[r] + v);
                }
                *(u64*)(hpb + goff[i]) = *(u64*)&o;
                *(u64*)((char*)bn + ebase + i * 4096) = *(u64*)&o;
            }
        }
        __syncthreads();
        bf16* tmp = bp; bp = bn; bn = tmp;
    }
}

__global__ __launch_bounds__(512, 2) void msg_fused(const bf16* __restrict__ Aw, bf16* __restrict__ hp) {
    __shared__ __align__(16) bf16 BUF[2][128 * 128];   // 2 x 32 KB ping-pong line buffers
    const int batch = blockIdx.x;
    bf16* hpb = hp + (size_t)batch * YS * XSZ * 128;
    // zero both buffers once (pad rows must start zero; full-row zero is
    // swizzle-invariant)
    for (int v = threadIdx.x; v < 2 * 128 * 16; v += 512)
        ((uint4*)BUF)[v] = uint4{0u, 0u, 0u, 0u};
    __syncthreads();
    bf16* bp = BUF[0];
    bf16* bn = BUF[1];
    phase1cu<2, 0>(Aw + 0 * 147456, hpb, bp, bn);
    phase1cu<2, 1>(Aw + 1 * 147456, hpb, bp, bn);
    phase1cu<3, 0>(Aw + 2 * 147456, hpb, bp, bn);
    phase1cu<3, 1>(Aw + 3 * 147456, hpb, bp, bn);
}

// ---------------- conv3 (1x1 128->5) + bias + softmax ----------------
__global__ __launch_bounds__(256) void conv3_softmax(const bf16* __restrict__ hp, const float* __restrict__ w2,
                                                     const float* __restrict__ b2, float* __restrict__ h5,
                                                     float* __restrict__ Pp) {
    int idx = blockIdx.x * 256 + threadIdx.x;
    if (idx >= PIX) return;
    int b = idx / 3600, rr = idx % 3600;
    int y = rr / 100, xx = rr % 100;
    const bf16* src = hp + ((size_t)(b * YS + y + 4) * XSZ + xx + 4) * 128;
    float a[5] = {b2[0], b2[1], b2[2], b2[3], b2[4]};
    for (int c8 = 0; c8 < 128; c8 += 8) {
        bf16x8 hv = *(const bf16x8*)(src + c8);
#pragma unroll
        for (int j = 0; j < 8; j++) {
            float hf = (float)hv[j];
            int c = c8 + j;
#pragma unroll
            for (int o = 0; o < 5; o++) a[o] += hf * w2[o * 128 + c];
        }
    }
    float mx = a[0];
#pragma unroll
    for (int o = 1; o < 5; o++) mx = a[o] > mx ? a[o] : mx;
    float e[5], sum = 0.f;
#pragma unroll
    for (int o = 0; o < 5; o++) { e[o] = expf(a[o] - mx); sum += e[o]; }
    float inv = 1.f / sum;
#pragma unroll
    for (int o = 0; o < 5; o++) {
        h5[(size_t)(b * 5 + o) * 3600 + rr] = a[o];
        Pp[(size_t)(b * 5 + o) * 3600 + rr] = e[o] * inv;
    }
}

__global__ __launch_bounds__(256) void pool_k(const float* __restrict__ Pp, float* __restrict__ F) {
    int idx = blockIdx.x * 256 + threadIdx.x;
    if (idx >= 36000) return;
    int xxp = idx % 50, r = idx / 50;
    int yyp = r % 18, bj = r / 18;
    int b = bj / 5, j = bj % 5;
    const float* Pb = Pp + (size_t)bj * 3600;
    float v = 0.25f * (Pb[(2 * yyp) * 100 + 2 * xxp] + Pb[(2 * yyp) * 100 + 2 * xxp + 1] +
                       Pb[(2 * yyp + 1) * 100 + 2 * xxp] + Pb[(2 * yyp + 1) * 100 + 2 * xxp + 1]);
    F[(size_t)b * 4500 + j * 900 + yyp * 50 + xxp] = v;
}

__global__ __launch_bounds__(64) void fc1_k(const float* __restrict__ F, const float* __restrict__ w,
                                            const float* __restrict__ bias, float* __restrict__ G) {
    int co = blockIdx.x;
    int lane = threadIdx.x;
    const float* wr = w + (size_t)co * 4500;
    float a[8] = {0.f, 0.f, 0.f, 0.f, 0.f, 0.f, 0.f, 0.f};
    for (int k = lane; k < 4500; k += 64) {
        float wv = wr[k];
#pragma unroll
        for (int b = 0; b < 8; b++) a[b] += wv * F[b * 4500 + k];
    }
#pragma unroll
    for (int b = 0; b < 8; b++) {
        float r = a[b];
        for (int off = 32; off; off >>= 1) r += __shfl_down(r, off);
        if (lane == 0) {
            float v = r + bias[co];
            G[b * 128 + co] = v > 0.f ? v : 0.f;
        }
    }
}

__global__ __launch_bounds__(64) void fc2_k(const float* __restrict__ G, const float* __restrict__ w,
                                            const float* __restrict__ bias, float* __restrict__ out) {
    int t = threadIdx.x;
    if (t >= 32) return;
    int b = t >> 2, j = t & 3;
    float a = bias[j];
    for (int c = 0; c < 128; c++) a += G[b * 128 + c] * w[j * 128 + c];
    out[9216000 + b * 4 + j] = 1.f / (1.f + expf(-a));
}

__global__ __launch_bounds__(256) void upsample_k(const float* __restrict__ h5, float* __restrict__ out) {
    int idx = blockIdx.x * 256 + threadIdx.x;
    if (idx >= 2304000) return;
    int xq = idx % 200, r = idx / 200;
    int yo = r % 288, bj = r / 288;
    const float* src = h5 + (size_t)bj * 3600;
    float py = yo * (35.0f / 287.0f);
    int i0 = (int)py; if (i0 > 34) i0 = 34;
    float fh = py - (float)i0;
    const float* r0 = src + i0 * 100;
    const float* r1 = r0 + 100;
    float4 o;
    float res[4];
#pragma unroll
    for (int e = 0; e < 4; e++) {
        int xo = xq * 4 + e;
        float px = xo * (99.0f / 799.0f);
        int j0 = (int)px; if (j0 > 98) j0 = 98;
        float fw = px - (float)j0;
        float aa = r0[j0] * (1.f - fh) + r1[j0] * fh;
        float bb = r0[j0 + 1] * (1.f - fh) + r1[j0 + 1] * fh;
        res[e] = aa * (1.f - fw) + bb * fw;
    }
    o.x = res[0]; o.y = res[1]; o.z = res[2]; o.w = res[3];
    *(float4*)(out + (size_t)idx * 4) = o;
}

// ---------------- launcher ----------------
extern "C" void kernel_launch(void* const* d_in, const int* in_sizes, int n_in,
                              void* d_out, int out_size, void* d_ws, size_t ws_size,
                              hipStream_t stream) {
    (void)in_sizes; (void)n_in; (void)out_size; (void)ws_size;
    const float* x    = (const float*)d_in[0];
    const float* w1a  = (const float*)d_in[1];
    const float* bn1g = (const float*)d_in[2];
    const float* bn1b = (const float*)d_in[3];
    const float* bn1m = (const float*)d_in[4];
    const float* bn1v = (const float*)d_in[5];
    const float* w1b  = (const float*)d_in[6];
    const float* bn2g = (const float*)d_in[7];
    const float* bn2b = (const float*)d_in[8];
    const float* bn2m = (const float*)d_in[9];
    const float* bn2v = (const float*)d_in[10];
    const float* wud  = (const float*)d_in[11];
    const float* wdu  = (const float*)d_in[12];
    const float* wlr  = (const float*)d_in[13];
    const float* wrl  = (const float*)d_in[14];
    const float* w2   = (const float*)d_in[15];
    const float* b2   = (const float*)d_in[16];
    const float* fc1w = (const float*)d_in[17];
    const float* fc1b = (const float*)d_in[18];
    const float* fc2w = (const float*)d_in[19];
    const float* fc2b = (const float*)d_in[20];
    float* out = (float*)d_out;
    char* ws = (char*)d_ws;
    bf16* xp = (bf16*)(ws + OFF_XP);
    bf16* hp = (bf16*)(ws + OFF_HP);
    bf16* A1 = (bf16*)(ws + OFF_A1);
    bf16* A2 = (bf16*)(ws + OFF_A2);
    bf16* Aw = (bf16*)(ws + OFF_AW);
    bf16* h1 = (bf16*)(ws + OFF_H1);
    float* s1 = (float*)(ws + OFF_S1);
    float* t1 = (float*)(ws + OFF_T1);
    float* s2 = (float*)(ws + OFF_S2);
    float* t2 = (float*)(ws + OFF_T2);
    float* h5 = (float*)(ws + OFF_H5);
    float* Pp = (float*)(ws + OFF_P);
    float* Ff = (float*)(ws + OFF_F);
    float* Gg = (float*)(ws + OFF_G);
    unsigned* bar = (unsigned*)(ws + OFF_BAR);

    int nzero = (int)((SZ_XP + SZ_HP) / 16);
    zero_k<<<(nzero + 255) / 256, 256, 0, stream>>>((uint4*)ws, nzero);
    prep_x<<<18432, 256, 0, stream>>>(x, xp);
    prep_w1a<<<1024, 256, 0, stream>>>(w1a, A1);
    prep_w1b<<<512, 256, 0, stream>>>(w1b, A2);
    prep_msg<<<2304, 256, 0, stream>>>(wud, wdu, wlr, wrl, Aw);
    prep_bn<<<5, 256, 0, stream>>>(bn1g, bn1b, bn1m, bn1v, bn2g, bn2b, bn2m, bn2v, s1, t1, s2, t2, bar);

    conv1_gemm<<<dim3(225, 8), 256, 0, stream>>>(A1, xp, s1, t1, h1);
    conv2_gemm<<<225, 256, 0, stream>>>(A2, h1, s2, t2, hp);

    msg_fused<<<8, 512, 0, stream>>>(Aw, hp);

    conv3_softmax<<<113, 256, 0, stream>>>(hp, w2, b2, h5, Pp);
    pool_k<<<141, 256, 0, stream>>>(Pp, Ff);
    fc1_k<<<128, 64, 0, stream>>>(Ff, fc1w, fc1b, Gg);
    fc2_k<<<1, 64, 0, stream>>>(Gg, fc2w, fc2b, out);
    upsample_k<<<9000, 256, 0, stream>>>(h5, out);
}